// Round 1
// baseline (553.541 us; speedup 1.0000x reference)
//
#include <hip/hip_runtime.h>
#include <float.h>
#include <math.h>

#define NN 8192
#define DH 256
#define KNN 10
#define TSTEPS 10
#define EPSC 0.1f
#define NSEG 16
#define SEGSZ (NN / NSEG)   // 512

typedef short s8v __attribute__((ext_vector_type(8)));
typedef float f4v __attribute__((ext_vector_type(4)));

__device__ __forceinline__ float bf2f(unsigned short u) {
    union { unsigned u; float f; } c; c.u = ((unsigned)u) << 16; return c.f;
}
__device__ __forceinline__ unsigned short f2bf(float f) {
    union { float f; unsigned u; } c; c.f = f;
    unsigned r = c.u + 0x7FFF + ((c.u >> 16) & 1);
    return (unsigned short)(r >> 16);
}

// Top-10 state as NAMED SCALARS (b0..b9 / i0..i9) — guaranteed VGPR-resident.
#define DECL_TOP10 \
    float b0=FLT_MAX,b1=FLT_MAX,b2=FLT_MAX,b3=FLT_MAX,b4=FLT_MAX, \
          b5=FLT_MAX,b6=FLT_MAX,b7=FLT_MAX,b8=FLT_MAX,b9=FLT_MAX; \
    int   i0=-1,i1=-1,i2=-1,i3=-1,i4=-1,i5=-1,i6=-1,i7=-1,i8=-1,i9=-1;

// Bubble insert: per rank exactly 5 VALU (v_cmp->vcc, v_min_f32, v_max_f32,
// 2x v_cndmask). Only ONE compare mask live at a time (consumed immediately
// by vcc) — the old rank-parallel network needed 10 live 64-bit masks and
// blew the 32-SGPR budget, forcing the compiler to recompute/serialize
// (~2x dynamic VALU). Strict '<' keeps earlier arrival (= lower index) on
// ties, identical semantics to the old network.
#define BSTEP(bk, ik) { \
    bool  _s  = _t < bk; \
    float _bn = fminf(bk, _t); \
    _t        = fmaxf(bk, _t); \
    int   _in = _s ? _it : ik; \
    _it       = _s ? ik : _it; \
    bk = _bn; ik = _in; \
}

#define BUBBLE10(dv, jv) do { \
    float _t = (dv); int _it = (jv); \
    BSTEP(b0, i0) BSTEP(b1, i1) BSTEP(b2, i2) BSTEP(b3, i3) BSTEP(b4, i4) \
    BSTEP(b5, i5) BSTEP(b6, i6) BSTEP(b7, i7) BSTEP(b8, i8) BSTEP(b9, i9) \
} while (0)

// ---------------- conv_ws [3][256][256] (k,n) -> bf16 Wt [3][n][k] ------------
__global__ void prep_wt(const float* __restrict__ W, unsigned short* __restrict__ Wt) {
    int e = blockIdx.x * 256 + threadIdx.x;
    int g = e >> 16; int rem = e & 65535;
    int n = rem >> 8; int k = rem & 255;
    Wt[e] = f2bf(W[g * 65536 + k * 256 + n]);
}

// ---------------- pos4[j] = {x, y, z, |p|^2} ----------------------------------
__global__ void prep_pos(const float* __restrict__ pos, float4* __restrict__ pos4) {
    int j = blockIdx.x * 256 + threadIdx.x;
    float x = pos[j * 3], y = pos[j * 3 + 1], z = pos[j * 3 + 2];
    float4 v; v.x = x; v.y = y; v.z = z; v.w = x * x + y * y + z * z;
    pos4[j] = v;
}

// ---------------- kNN pass 1: per-(query, segment) top-10 ---------------------
__launch_bounds__(256)
__global__ void knn_scan(const float* __restrict__ pos, const float4* __restrict__ pos4,
                         uint2* __restrict__ segdj) {
    __shared__ float4 cand[SEGSZ];
    int qb = blockIdx.x >> 4, seg = blockIdx.x & 15;
    int tid = threadIdx.x;
    int i = qb * 256 + tid;
    for (int t = tid; t < SEGSZ; t += 256) cand[t] = pos4[seg * SEGSZ + t];
    float xi = pos[i * 3], yi = pos[i * 3 + 1], zi = pos[i * 3 + 2];
    float sqi = xi * xi + yi * yi + zi * zi;
    __syncthreads();

    DECL_TOP10;
    int jbase = seg * SEGSZ;
#pragma unroll 4
    for (int t = 0; t < SEGSZ; t++) {
        float4 c = cand[t];
        float m = c.x * xi + c.y * yi + c.z * zi;
        float d = (sqi + c.w) - 2.0f * m;
        int j = jbase + t;
        if (j == i) d = FLT_MAX;          // cmp+cndmask, branchless
        BUBBLE10(d, j);
    }
    uint2* op = segdj + (seg * NN + i) * KNN;
    op[0] = make_uint2(__float_as_uint(b0), (unsigned)i0);
    op[1] = make_uint2(__float_as_uint(b1), (unsigned)i1);
    op[2] = make_uint2(__float_as_uint(b2), (unsigned)i2);
    op[3] = make_uint2(__float_as_uint(b3), (unsigned)i3);
    op[4] = make_uint2(__float_as_uint(b4), (unsigned)i4);
    op[5] = make_uint2(__float_as_uint(b5), (unsigned)i5);
    op[6] = make_uint2(__float_as_uint(b6), (unsigned)i6);
    op[7] = make_uint2(__float_as_uint(b7), (unsigned)i7);
    op[8] = make_uint2(__float_as_uint(b8), (unsigned)i8);
    op[9] = make_uint2(__float_as_uint(b9), (unsigned)i9);
}

// ---------------- kNN pass 2: merge 16 sorted lists -> final top-10 -----------
__global__ void knn_merge(const uint2* __restrict__ segdj, int* __restrict__ nbr) {
    int i = blockIdx.x * 256 + threadIdx.x;
    DECL_TOP10;
    for (int s = 0; s < NSEG; s++) {       // ascending seg = ascending index on ties
        const uint2* p = segdj + (s * NN + i) * KNN;
#pragma unroll
        for (int q = 0; q < KNN; q++) {
            uint2 v = p[q];
            BUBBLE10(__uint_as_float(v.x), (int)v.y);
        }
    }
    int* np = nbr + i * KNN;
    np[0] = i0; np[1] = i1; np[2] = i2; np[3] = i3; np[4] = i4;
    np[5] = i5; np[6] = i6; np[7] = i7; np[8] = i8; np[9] = i9;
}

// ---------------- h = lm@emb_w + emb_b ; x = h@rw + rb ------------------------
__global__ void emb_kernel(const float* __restrict__ lm, const float* __restrict__ ew,
                           const float* __restrict__ eb, const float* __restrict__ rw,
                           const float* __restrict__ rb,
                           float* __restrict__ hdo, unsigned short* __restrict__ hbf,
                           float* __restrict__ xout) {
    __shared__ float s0[4], s1[4], s2[4];
    int i = blockIdx.x, d = threadIdx.x;
    float a0 = lm[i * 3], a1 = lm[i * 3 + 1], a2 = lm[i * 3 + 2];
    float h = eb[d] + a0 * ew[d] + a1 * ew[256 + d] + a2 * ew[512 + d];
    hdo[i * 256 + d] = h;
    hbf[i * 256 + d] = f2bf(h);
    float p0 = h * rw[d * 3], p1 = h * rw[d * 3 + 1], p2 = h * rw[d * 3 + 2];
    for (int off = 32; off; off >>= 1) {
        p0 += __shfl_down(p0, off, 64);
        p1 += __shfl_down(p1, off, 64);
        p2 += __shfl_down(p2, off, 64);
    }
    int lane = d & 63, wid = d >> 6;
    if (lane == 0) { s0[wid] = p0; s1[wid] = p1; s2[wid] = p2; }
    __syncthreads();
    if (d == 0) {
        xout[i * 3 + 0] = s0[0] + s0[1] + s0[2] + s0[3] + rb[0];
        xout[i * 3 + 1] = s1[0] + s1[1] + s1[2] + s1[3] + rb[1];
        xout[i * 3 + 2] = s2[0] + s2[1] + s2[2] + s2[3] + rb[2];
    }
}

// ---------------- hop-1: x1[i] = 0.1 * sum_{j in nbr(i)} hbf[j] ---------------
__global__ void agg_kernel(const unsigned short* __restrict__ src,
                           unsigned short* __restrict__ dst,
                           const int* __restrict__ nbr) {
    int tid = threadIdx.x;
    int wid = tid >> 6, lane = tid & 63;
    int node = blockIdx.x * 4 + wid;
    int d0 = lane * 4;
    float a0 = 0.f, a1 = 0.f, a2 = 0.f, a3 = 0.f;
    const int* nb = nbr + node * KNN;
    for (int q = 0; q < KNN; q++) {
        int j = nb[q];
        uint2 v = *(const uint2*)(src + j * 256 + d0);
        a0 += bf2f((unsigned short)(v.x & 0xffff));
        a1 += bf2f((unsigned short)(v.x >> 16));
        a2 += bf2f((unsigned short)(v.y & 0xffff));
        a3 += bf2f((unsigned short)(v.y >> 16));
    }
    uint2 o;
    o.x = (unsigned)f2bf(a0 * 0.1f) | ((unsigned)f2bf(a1 * 0.1f) << 16);
    o.y = (unsigned)f2bf(a2 * 0.1f) | ((unsigned)f2bf(a3 * 0.1f) << 16);
    *(uint2*)(dst + node * 256 + d0) = o;
}

// ------- fused: hop-2 gather (x2 tile in LDS) + GEMM + Euler + readout --------
__launch_bounds__(256)
__global__ void gemm_step(unsigned short* hbf,
                          const unsigned short* __restrict__ x1,
                          const int* __restrict__ nbr,
                          const unsigned short* __restrict__ Wt,
                          const float* __restrict__ cb,
                          const float* __restrict__ rw, const float* __restrict__ rb,
                          float* hdo, float* __restrict__ yout, float* yfin) {
    __shared__ __align__(16) short Al[32 * 72];
    __shared__ __align__(16) short Bl[256 * 72];
    __shared__ __align__(16) short X2[32 * 264];
    __shared__ float rwl[768];
    __shared__ float cbl[256];
    __shared__ float yred[2][2][4][4][3];

    int tid = threadIdx.x;
    int m0 = blockIdx.x * 32;
    for (int idx = tid; idx < 768; idx += 256) rwl[idx] = rw[idx];
    cbl[tid] = cb[tid];

    // ---- fused hop-2 aggregation: X2[row][:] = bf16(0.1 * sum x1[nbr[row]]) ----
    {
        int row = tid >> 3, cg = tid & 7;
        const int* nb = nbr + (m0 + row) * KNN;
        float a[32];
#pragma unroll
        for (int e = 0; e < 32; e++) a[e] = 0.f;
        for (int q = 0; q < KNN; q++) {
            int j = nb[q];
            const uint4* p = (const uint4*)(x1 + j * 256 + cg * 32);
#pragma unroll
            for (int u = 0; u < 4; u++) {
                uint4 v = p[u];
                unsigned w0 = v.x, w1 = v.y, w2 = v.z, w3 = v.w;
                a[u*8+0] += bf2f((unsigned short)(w0 & 0xffff));
                a[u*8+1] += bf2f((unsigned short)(w0 >> 16));
                a[u*8+2] += bf2f((unsigned short)(w1 & 0xffff));
                a[u*8+3] += bf2f((unsigned short)(w1 >> 16));
                a[u*8+4] += bf2f((unsigned short)(w2 & 0xffff));
                a[u*8+5] += bf2f((unsigned short)(w2 >> 16));
                a[u*8+6] += bf2f((unsigned short)(w3 & 0xffff));
                a[u*8+7] += bf2f((unsigned short)(w3 >> 16));
            }
        }
        unsigned short* xp = (unsigned short*)&X2[row * 264 + cg * 32];
#pragma unroll
        for (int u = 0; u < 4; u++) {
            uint2 o;
            o.x = (unsigned)f2bf(a[u*8+0]*0.1f) | ((unsigned)f2bf(a[u*8+1]*0.1f) << 16);
            o.y = (unsigned)f2bf(a[u*8+2]*0.1f) | ((unsigned)f2bf(a[u*8+3]*0.1f) << 16);
            uint2 o2;
            o2.x = (unsigned)f2bf(a[u*8+4]*0.1f) | ((unsigned)f2bf(a[u*8+5]*0.1f) << 16);
            o2.y = (unsigned)f2bf(a[u*8+6]*0.1f) | ((unsigned)f2bf(a[u*8+7]*0.1f) << 16);
            *(uint2*)(xp + u * 8) = o;
            *(uint2*)(xp + u * 8 + 4) = o2;
        }
    }

    f4v acc[8];
    for (int f = 0; f < 8; f++) acc[f] = (f4v){0.f, 0.f, 0.f, 0.f};

    int w = tid >> 6, lane = tid & 63;
    int rowgrp = w & 1, nhalf = w >> 1;
    int quad = lane >> 4, l15 = lane & 15;

    for (int kc = 0; kc < 12; kc++) {
        int kb = kc * 64;
        int klocal = kb & 255;
        if (kc < 8) {
            const unsigned short* asrc = (kb < 256) ? (const unsigned short*)hbf : x1;
            int row = tid >> 3, c8 = (tid & 7) * 8;
            uint4 v = *(const uint4*)(asrc + (m0 + row) * 256 + klocal + c8);
            *(uint4*)(&Al[row * 72 + c8]) = v;
        }
        {
            const unsigned short* bsrc = Wt + (kb >> 8) * 65536;
            int c8 = (tid & 7) * 8, rbase = tid >> 3;
            for (int r2 = 0; r2 < 8; r2++) {
                int n = r2 * 32 + rbase;
                uint4 v = *(const uint4*)(bsrc + n * 256 + klocal + c8);
                *(uint4*)(&Bl[n * 72 + c8]) = v;
            }
        }
        __syncthreads();
        for (int ks = 0; ks < 2; ks++) {
            s8v a;
            if (kc < 8)
                a = *(const s8v*)(&Al[(rowgrp * 16 + l15) * 72 + ks * 32 + quad * 8]);
            else
                a = *(const s8v*)(&X2[(rowgrp * 16 + l15) * 264 + klocal + ks * 32 + quad * 8]);
            for (int f = 0; f < 8; f++) {
                int n = nhalf * 128 + f * 16 + l15;
                s8v b = *(const s8v*)(&Bl[n * 72 + ks * 32 + quad * 8]);
                acc[f] = __builtin_amdgcn_mfma_f32_16x16x32_bf16(a, b, acc[f], 0, 0, 0);
            }
        }
        __syncthreads();
    }

    float py[4][3] = {};
    for (int f = 0; f < 8; f++) {
        int col = nhalf * 128 + f * 16 + l15;
        float cbv = cbl[col];
        float rw0 = rwl[col * 3], rw1 = rwl[col * 3 + 1], rw2 = rwl[col * 3 + 2];
        for (int r = 0; r < 4; r++) {
            int grow = m0 + rowgrp * 16 + quad * 4 + r;
            float cval = acc[f][r] + cbv;
            float hn = hdo[grow * 256 + col] + EPSC * tanhf(cval);
            hdo[grow * 256 + col] = hn;
            hbf[grow * 256 + col] = f2bf(hn);
            py[r][0] += hn * rw0; py[r][1] += hn * rw1; py[r][2] += hn * rw2;
        }
    }
    for (int off = 1; off < 16; off <<= 1)
        for (int r = 0; r < 4; r++)
            for (int j = 0; j < 3; j++)
                py[r][j] += __shfl_xor(py[r][j], off, 64);
    if (l15 == 0)
        for (int r = 0; r < 4; r++)
            for (int j = 0; j < 3; j++)
                yred[rowgrp][nhalf][quad][r][j] = py[r][j];
    __syncthreads();
    if (nhalf == 0 && l15 == 0) {
        for (int r = 0; r < 4; r++) {
            int grow = m0 + rowgrp * 16 + quad * 4 + r;
            for (int j = 0; j < 3; j++) {
                float yv = yred[rowgrp][0][quad][r][j] + yred[rowgrp][1][quad][r][j] + rb[j];
                yout[grow * 3 + j] = yv;
                if (yfin) yfin[grow * 3 + j] = yv;
            }
        }
    }
}

extern "C" void kernel_launch(void* const* d_in, const int* in_sizes, int n_in,
                              void* d_out, int out_size, void* d_ws, size_t ws_size,
                              hipStream_t stream) {
    const float* lm = (const float*)d_in[0];
    const float* ew = (const float*)d_in[1];
    const float* eb = (const float*)d_in[2];
    const float* rw = (const float*)d_in[3];
    const float* rb = (const float*)d_in[4];
    const float* cw = (const float*)d_in[5];
    const float* cb = (const float*)d_in[6];

    float* out = (float*)d_out;
    float* y_out = out;
    float* h_out = out + 24576;
    float* x_out = out + 24576 + 2097152;
    float* lp_out = x_out + 24576;

    char* ws = (char*)d_ws;
    int* nbr = (int*)ws;                       ws += NN * KNN * sizeof(int);
    float4* pos4 = (float4*)ws;                ws += NN * sizeof(float4);
    char* uni = ws;
    uint2* segdj = (uint2*)uni;
    unsigned short* hbf = (unsigned short*)uni;
    unsigned short* x1  = hbf + NN * DH;
    unsigned short* Wt  = x1 + NN * DH;

    prep_pos<<<NN / 256, 256, 0, stream>>>(lm, pos4);
    knn_scan<<<32 * NSEG, 256, 0, stream>>>(lm, pos4, segdj);
    knn_merge<<<NN / 256, 256, 0, stream>>>(segdj, nbr);
    prep_wt<<<768, 256, 0, stream>>>(cw, Wt);
    emb_kernel<<<NN, 256, 0, stream>>>(lm, ew, eb, rw, rb, h_out, hbf, x_out);
    for (int t = 0; t < TSTEPS; t++) {
        agg_kernel<<<NN / 4, 256, 0, stream>>>(hbf, x1, nbr);
        gemm_step<<<NN / 32, 256, 0, stream>>>(hbf, x1, nbr, Wt, cb, rw, rb, h_out,
                                               lp_out + t * 24576,
                                               (t == TSTEPS - 1) ? y_out : nullptr);
    }
}

// Round 2
// 488.885 us; speedup vs baseline: 1.1323x; 1.1323x over previous
//
#include <hip/hip_runtime.h>
#include <float.h>
#include <math.h>

#define NN 8192
#define DH 256
#define KNN 10
#define TSTEPS 10
#define EPSC 0.1f
#define CTILE 1024          // candidates staged in LDS per tile

typedef short s8v __attribute__((ext_vector_type(8)));
typedef float f4v __attribute__((ext_vector_type(4)));

__device__ __forceinline__ float bf2f(unsigned short u) {
    union { unsigned u; float f; } c; c.u = ((unsigned)u) << 16; return c.f;
}
__device__ __forceinline__ unsigned short f2bf(float f) {
    union { float f; unsigned u; } c; c.f = f;
    unsigned r = c.u + 0x7FFF + ((c.u >> 16) & 1);
    return (unsigned short)(r >> 16);
}

// ---------------- conv_ws [3][256][256] (k,n) -> bf16 Wt [3][n][k] ------------
__global__ void prep_wt(const float* __restrict__ W, unsigned short* __restrict__ Wt) {
    int e = blockIdx.x * 256 + threadIdx.x;
    int g = e >> 16; int rem = e & 65535;
    int n = rem >> 8; int k = rem & 255;
    Wt[e] = f2bf(W[g * 65536 + k * 256 + n]);
}

// ---------------- pos4[j] = {x, y, z, |p|^2} ----------------------------------
__global__ void prep_pos(const float* __restrict__ pos, float4* __restrict__ pos4) {
    int j = blockIdx.x * 256 + threadIdx.x;
    float x = pos[j * 3], y = pos[j * 3 + 1], z = pos[j * 3 + 2];
    float4 v; v.x = x; v.y = y; v.z = z; v.w = x * x + y * y + z * z;
    pos4[j] = v;
}

// ---------------- kNN: ONE WAVE PER QUERY, coherent threshold early-out -------
// Each wave owns one query. Lanes scan 64 candidates/batch; the wave-uniform
// threshold thr (current 10th-best) filters candidates BEFORE any insert work.
// Expected inserts per query: ~10 + 10*ln(8192/10) ~ 77 out of 8192 candidates.
// Top-10 is DISTRIBUTED: rank r lives in lane r (sorted ascending). An insert
// is a shfl_up shift + 2 cmp + 4 cndmask (~10 slots), wave-uniform.
// Candidates processed in ascending j; strict '<' => lower index wins ties,
// matching jax.lax.top_k stability.
__launch_bounds__(256)
__global__ void knn_wave(const float* __restrict__ pos, const float4* __restrict__ pos4,
                         int* __restrict__ nbr) {
    __shared__ float4 cand[CTILE];
    int tid = threadIdx.x;
    int wv = tid >> 6, lane = tid & 63;
    int i = blockIdx.x * 4 + wv;                 // query for this wave
    float xi = pos[i * 3], yi = pos[i * 3 + 1], zi = pos[i * 3 + 2];
    float sqi = xi * xi + yi * yi + zi * zi;

    float b = FLT_MAX;                           // rank 'lane' best-distance
    int   ib = -1;                               // rank 'lane' index
    float thr = FLT_MAX;                         // wave-uniform 10th best

    for (int tile = 0; tile < NN / CTILE; ++tile) {
        __syncthreads();
        for (int t = tid; t < CTILE; t += 256) cand[t] = pos4[tile * CTILE + t];
        __syncthreads();
#pragma unroll 4
        for (int u = 0; u < CTILE / 64; ++u) {
            float4 c = cand[u * 64 + lane];
            int j = tile * CTILE + u * 64 + lane;
            float m = c.x * xi + c.y * yi + c.z * zi;
            float d = (sqi + c.w) - 2.0f * m;
            if (j == i) d = FLT_MAX;             // self-exclusion, branchless
            unsigned long long mask = __ballot(d < thr);
            while (mask) {
                int l = __ffsll(mask) - 1;
                mask &= mask - 1;
                float dc = __shfl(d, l, 64);     // broadcast candidate
                if (dc < thr) {                  // re-check vs updated thr (uniform)
                    int jc = __shfl(j, l, 64);
                    float bp = __shfl_up(b, 1, 64);
                    int   ip = __shfl_up(ib, 1, 64);
                    bool c0 = dc < b;                        // insert at/below my rank
                    bool cp = (lane != 0) && (dc < bp);      // insert strictly below
                    b  = c0 ? (cp ? bp : dc) : b;
                    ib = c0 ? (cp ? ip : jc) : ib;
                    thr = __shfl(b, KNN - 1, 64);            // new 10th best
                }
            }
        }
    }
    if (lane < KNN) nbr[i * KNN + lane] = ib;
}

// ---------------- h = lm@emb_w + emb_b ; x = h@rw + rb ------------------------
__global__ void emb_kernel(const float* __restrict__ lm, const float* __restrict__ ew,
                           const float* __restrict__ eb, const float* __restrict__ rw,
                           const float* __restrict__ rb,
                           float* __restrict__ hdo, unsigned short* __restrict__ hbf,
                           float* __restrict__ xout) {
    __shared__ float s0[4], s1[4], s2[4];
    int i = blockIdx.x, d = threadIdx.x;
    float a0 = lm[i * 3], a1 = lm[i * 3 + 1], a2 = lm[i * 3 + 2];
    float h = eb[d] + a0 * ew[d] + a1 * ew[256 + d] + a2 * ew[512 + d];
    hdo[i * 256 + d] = h;
    hbf[i * 256 + d] = f2bf(h);
    float p0 = h * rw[d * 3], p1 = h * rw[d * 3 + 1], p2 = h * rw[d * 3 + 2];
    for (int off = 32; off; off >>= 1) {
        p0 += __shfl_down(p0, off, 64);
        p1 += __shfl_down(p1, off, 64);
        p2 += __shfl_down(p2, off, 64);
    }
    int lane = d & 63, wid = d >> 6;
    if (lane == 0) { s0[wid] = p0; s1[wid] = p1; s2[wid] = p2; }
    __syncthreads();
    if (d == 0) {
        xout[i * 3 + 0] = s0[0] + s0[1] + s0[2] + s0[3] + rb[0];
        xout[i * 3 + 1] = s1[0] + s1[1] + s1[2] + s1[3] + rb[1];
        xout[i * 3 + 2] = s2[0] + s2[1] + s2[2] + s2[3] + rb[2];
    }
}

// ---------------- hop-1: x1[i] = 0.1 * sum_{j in nbr(i)} hbf[j] ---------------
__global__ void agg_kernel(const unsigned short* __restrict__ src,
                           unsigned short* __restrict__ dst,
                           const int* __restrict__ nbr) {
    int tid = threadIdx.x;
    int wid = tid >> 6, lane = tid & 63;
    int node = blockIdx.x * 4 + wid;
    int d0 = lane * 4;
    float a0 = 0.f, a1 = 0.f, a2 = 0.f, a3 = 0.f;
    const int* nb = nbr + node * KNN;
    for (int q = 0; q < KNN; q++) {
        int j = nb[q];
        uint2 v = *(const uint2*)(src + j * 256 + d0);
        a0 += bf2f((unsigned short)(v.x & 0xffff));
        a1 += bf2f((unsigned short)(v.x >> 16));
        a2 += bf2f((unsigned short)(v.y & 0xffff));
        a3 += bf2f((unsigned short)(v.y >> 16));
    }
    uint2 o;
    o.x = (unsigned)f2bf(a0 * 0.1f) | ((unsigned)f2bf(a1 * 0.1f) << 16);
    o.y = (unsigned)f2bf(a2 * 0.1f) | ((unsigned)f2bf(a3 * 0.1f) << 16);
    *(uint2*)(dst + node * 256 + d0) = o;
}

// ------- fused: hop-2 gather (x2 tile in LDS) + GEMM + Euler + readout --------
__launch_bounds__(256)
__global__ void gemm_step(unsigned short* hbf,
                          const unsigned short* __restrict__ x1,
                          const int* __restrict__ nbr,
                          const unsigned short* __restrict__ Wt,
                          const float* __restrict__ cb,
                          const float* __restrict__ rw, const float* __restrict__ rb,
                          float* hdo, float* __restrict__ yout, float* yfin) {
    __shared__ __align__(16) short Al[32 * 72];
    __shared__ __align__(16) short Bl[256 * 72];
    __shared__ __align__(16) short X2[32 * 264];
    __shared__ float rwl[768];
    __shared__ float cbl[256];
    __shared__ float yred[2][2][4][4][3];

    int tid = threadIdx.x;
    int m0 = blockIdx.x * 32;
    for (int idx = tid; idx < 768; idx += 256) rwl[idx] = rw[idx];
    cbl[tid] = cb[tid];

    // ---- fused hop-2 aggregation: X2[row][:] = bf16(0.1 * sum x1[nbr[row]]) ----
    {
        int row = tid >> 3, cg = tid & 7;
        const int* nb = nbr + (m0 + row) * KNN;
        float a[32];
#pragma unroll
        for (int e = 0; e < 32; e++) a[e] = 0.f;
        for (int q = 0; q < KNN; q++) {
            int j = nb[q];
            const uint4* p = (const uint4*)(x1 + j * 256 + cg * 32);
#pragma unroll
            for (int u = 0; u < 4; u++) {
                uint4 v = p[u];
                unsigned w0 = v.x, w1 = v.y, w2 = v.z, w3 = v.w;
                a[u*8+0] += bf2f((unsigned short)(w0 & 0xffff));
                a[u*8+1] += bf2f((unsigned short)(w0 >> 16));
                a[u*8+2] += bf2f((unsigned short)(w1 & 0xffff));
                a[u*8+3] += bf2f((unsigned short)(w1 >> 16));
                a[u*8+4] += bf2f((unsigned short)(w2 & 0xffff));
                a[u*8+5] += bf2f((unsigned short)(w2 >> 16));
                a[u*8+6] += bf2f((unsigned short)(w3 & 0xffff));
                a[u*8+7] += bf2f((unsigned short)(w3 >> 16));
            }
        }
        unsigned short* xp = (unsigned short*)&X2[row * 264 + cg * 32];
#pragma unroll
        for (int u = 0; u < 4; u++) {
            uint2 o;
            o.x = (unsigned)f2bf(a[u*8+0]*0.1f) | ((unsigned)f2bf(a[u*8+1]*0.1f) << 16);
            o.y = (unsigned)f2bf(a[u*8+2]*0.1f) | ((unsigned)f2bf(a[u*8+3]*0.1f) << 16);
            uint2 o2;
            o2.x = (unsigned)f2bf(a[u*8+4]*0.1f) | ((unsigned)f2bf(a[u*8+5]*0.1f) << 16);
            o2.y = (unsigned)f2bf(a[u*8+6]*0.1f) | ((unsigned)f2bf(a[u*8+7]*0.1f) << 16);
            *(uint2*)(xp + u * 8) = o;
            *(uint2*)(xp + u * 8 + 4) = o2;
        }
    }

    f4v acc[8];
    for (int f = 0; f < 8; f++) acc[f] = (f4v){0.f, 0.f, 0.f, 0.f};

    int w = tid >> 6, lane = tid & 63;
    int rowgrp = w & 1, nhalf = w >> 1;
    int quad = lane >> 4, l15 = lane & 15;

    for (int kc = 0; kc < 12; kc++) {
        int kb = kc * 64;
        int klocal = kb & 255;
        if (kc < 8) {
            const unsigned short* asrc = (kb < 256) ? (const unsigned short*)hbf : x1;
            int row = tid >> 3, c8 = (tid & 7) * 8;
            uint4 v = *(const uint4*)(asrc + (m0 + row) * 256 + klocal + c8);
            *(uint4*)(&Al[row * 72 + c8]) = v;
        }
        {
            const unsigned short* bsrc = Wt + (kb >> 8) * 65536;
            int c8 = (tid & 7) * 8, rbase = tid >> 3;
            for (int r2 = 0; r2 < 8; r2++) {
                int n = r2 * 32 + rbase;
                uint4 v = *(const uint4*)(bsrc + n * 256 + klocal + c8);
                *(uint4*)(&Bl[n * 72 + c8]) = v;
            }
        }
        __syncthreads();
        for (int ks = 0; ks < 2; ks++) {
            s8v a;
            if (kc < 8)
                a = *(const s8v*)(&Al[(rowgrp * 16 + l15) * 72 + ks * 32 + quad * 8]);
            else
                a = *(const s8v*)(&X2[(rowgrp * 16 + l15) * 264 + klocal + ks * 32 + quad * 8]);
            for (int f = 0; f < 8; f++) {
                int n = nhalf * 128 + f * 16 + l15;
                s8v b = *(const s8v*)(&Bl[n * 72 + ks * 32 + quad * 8]);
                acc[f] = __builtin_amdgcn_mfma_f32_16x16x32_bf16(a, b, acc[f], 0, 0, 0);
            }
        }
        __syncthreads();
    }

    float py[4][3] = {};
    for (int f = 0; f < 8; f++) {
        int col = nhalf * 128 + f * 16 + l15;
        float cbv = cbl[col];
        float rw0 = rwl[col * 3], rw1 = rwl[col * 3 + 1], rw2 = rwl[col * 3 + 2];
        for (int r = 0; r < 4; r++) {
            int grow = m0 + rowgrp * 16 + quad * 4 + r;
            float cval = acc[f][r] + cbv;
            float hn = hdo[grow * 256 + col] + EPSC * tanhf(cval);
            hdo[grow * 256 + col] = hn;
            hbf[grow * 256 + col] = f2bf(hn);
            py[r][0] += hn * rw0; py[r][1] += hn * rw1; py[r][2] += hn * rw2;
        }
    }
    for (int off = 1; off < 16; off <<= 1)
        for (int r = 0; r < 4; r++)
            for (int j = 0; j < 3; j++)
                py[r][j] += __shfl_xor(py[r][j], off, 64);
    if (l15 == 0)
        for (int r = 0; r < 4; r++)
            for (int j = 0; j < 3; j++)
                yred[rowgrp][nhalf][quad][r][j] = py[r][j];
    __syncthreads();
    if (nhalf == 0 && l15 == 0) {
        for (int r = 0; r < 4; r++) {
            int grow = m0 + rowgrp * 16 + quad * 4 + r;
            for (int j = 0; j < 3; j++) {
                float yv = yred[rowgrp][0][quad][r][j] + yred[rowgrp][1][quad][r][j] + rb[j];
                yout[grow * 3 + j] = yv;
                if (yfin) yfin[grow * 3 + j] = yv;
            }
        }
    }
}

extern "C" void kernel_launch(void* const* d_in, const int* in_sizes, int n_in,
                              void* d_out, int out_size, void* d_ws, size_t ws_size,
                              hipStream_t stream) {
    const float* lm = (const float*)d_in[0];
    const float* ew = (const float*)d_in[1];
    const float* eb = (const float*)d_in[2];
    const float* rw = (const float*)d_in[3];
    const float* rb = (const float*)d_in[4];
    const float* cw = (const float*)d_in[5];
    const float* cb = (const float*)d_in[6];

    float* out = (float*)d_out;
    float* y_out = out;
    float* h_out = out + 24576;
    float* x_out = out + 24576 + 2097152;
    float* lp_out = x_out + 24576;

    char* ws = (char*)d_ws;
    int* nbr = (int*)ws;                       ws += NN * KNN * sizeof(int);
    float4* pos4 = (float4*)ws;                ws += NN * sizeof(float4);
    char* uni = ws;
    unsigned short* hbf = (unsigned short*)uni;
    unsigned short* x1  = hbf + NN * DH;
    unsigned short* Wt  = x1 + NN * DH;

    prep_pos<<<NN / 256, 256, 0, stream>>>(lm, pos4);
    knn_wave<<<NN / 4, 256, 0, stream>>>(lm, pos4, nbr);
    prep_wt<<<768, 256, 0, stream>>>(cw, Wt);
    emb_kernel<<<NN, 256, 0, stream>>>(lm, ew, eb, rw, rb, h_out, hbf, x_out);
    for (int t = 0; t < TSTEPS; t++) {
        agg_kernel<<<NN / 4, 256, 0, stream>>>(hbf, x1, nbr);
        gemm_step<<<NN / 32, 256, 0, stream>>>(hbf, x1, nbr, Wt, cb, rw, rb, h_out,
                                               lp_out + t * 24576,
                                               (t == TSTEPS - 1) ? y_out : nullptr);
    }
}